// Round 5
// baseline (556.498 us; speedup 1.0000x reference)
//
#include <hip/hip_runtime.h>

typedef _Float16 half8 __attribute__((ext_vector_type(8)));
typedef float floatx4 __attribute__((ext_vector_type(4)));

#define K_ 3
#define N_ 16384
#define M_ 4096
#define D_ 128
#define H_ 64

// workspace layout (bytes)
#define OFF_FXH 0
#define SZ_FXH (K_*N_*H_*2)
#define OFF_FZH (OFF_FXH + SZ_FXH)
#define SZ_FZH (K_*M_*H_*2)
#define OFF_NXS (OFF_FZH + SZ_FZH)
#define SZ_NXS (K_*N_*4)
#define OFF_NZS (OFF_NXS + SZ_NXS)
#define SZ_NZS (K_*M_*4)
#define OFF_W1T (OFF_NZS + SZ_NZS)
#define SZ_W1T (K_*D_*H_*4)
#define OFF_W2T (OFF_W1T + SZ_W1T)
#define SZ_W2T (K_*H_*H_*4)
#define OFF_W3T (OFF_W2T + SZ_W2T)

// ATTRIBUTION ROUND: dkef_main is idempotent (pure function of workspace ->
// out). It is launched 4x; dkef_dur = (dur_us - 356.3)/3 vs the byte-identical
// round-4 build. phi/transpose/fill attribution follows by subtraction.

// fxh/fzh are stored FRAGMENT-NATIVE: for each k and 16-row chunk c,
// a 1024-half (2 KB) tile laid out [ks(2)][fq(4)][fr(16)][e(8)] where
// element (row, h) lives at ks=h/32, fq=(h%32)/8, fr=row%16, e=h%8.
// A dkef MFMA fragment load (lane&15=fr, lane>>4=fq) is then
// 64 lanes x 16 B = 1024 B CONTIGUOUS -> 8 full cache lines.

// ---------------- weight transpose (tiny) ----------------
__global__ void transpose_w(const float* __restrict__ W1,
                            const float* __restrict__ W2,
                            const float* __restrict__ W3,
                            float* __restrict__ W1t,
                            float* __restrict__ W2t,
                            float* __restrict__ W3t) {
  int idx = blockIdx.x * 256 + threadIdx.x;
  if (idx < K_*H_*D_) {   // W1[k][h][d] -> W1t[k][d][h]
    int k = idx / (H_*D_); int r = idx % (H_*D_);
    int h = r / D_; int d = r % D_;
    W1t[k*(D_*H_) + d*H_ + h] = W1[idx];
  }
  if (idx < K_*H_*H_) {   // W2[k][g][h] -> W2t[k][h][g]; same for W3
    int k = idx / (H_*H_); int r = idx % (H_*H_);
    int g = r / H_; int h = r % H_;
    W2t[k*(H_*H_) + h*H_ + g] = W2[idx];
    W3t[k*(H_*H_) + h*H_ + g] = W3[idx];
  }
}

// ---------------- phi: fused 3-layer MLP, fp32, scale + fp16 round + norms ----------------
__device__ __forceinline__ float softplus_f(float x) {
  float p = exp2f(x * 1.44269504089f);
  float r = 0.693147180560f * log2f(1.0f + p);
  return (x > 20.0f) ? x : r;
}

__global__ __launch_bounds__(256) void phi_kernel(
    const float* __restrict__ x, const float* __restrict__ z,
    const float* __restrict__ W1t, const float* __restrict__ b1,
    const float* __restrict__ W2t, const float* __restrict__ b2,
    const float* __restrict__ W3t, const float* __restrict__ b3,
    const float* __restrict__ log_sigma,
    _Float16* __restrict__ fxh, float* __restrict__ nxs,
    _Float16* __restrict__ fzh, float* __restrict__ nzs)
{
  // xbuf pad 132 (= 4 mod 32 dwords): wave64 float4 reads land 8/bank = LDS min
  __shared__ float xbuf[64*132];  // 64 rows x 128 d, coalesced-staged
  __shared__ float hbuf[64*68];   // 64 rows x 64 h, pad to 68
  __shared__ float nred[64*4];

  const int which = blockIdx.z;   // 0 -> x, 1 -> z
  const int nrows = which ? M_ : N_;
  if (blockIdx.x * 64 >= nrows) return;
  const float* __restrict__ src = which ? z : x;
  _Float16* __restrict__ dsth = which ? fzh : fxh;
  float* __restrict__ dstn = which ? nzs : nxs;

  const int t = threadIdx.x;
  const int lane = t & 63;
  const int wv = __builtin_amdgcn_readfirstlane(t >> 6); // wave id, uniform -> scalar weight loads
  const int k = blockIdx.y;
  const int row0 = blockIdx.x * 64;
  const int row = row0 + lane;
  const int h0 = wv * 16;

  const float* __restrict__ w1 = W1t + k*(D_*H_);
  const float* __restrict__ w2 = W2t + k*(H_*H_);
  const float* __restrict__ w3 = W3t + k*(H_*H_);

  // ---- coalesced stage of the 64x128 fp32 input tile
  {
    const float4* __restrict__ gx = (const float4*)(src + (size_t)row0 * D_);
    #pragma unroll
    for (int it = 0; it < 8; it++) {
      int idx = t + it*256;          // 0..2047 float4s; 32 float4 per row
      int r = idx >> 5, c = idx & 31;
      *(float4*)&xbuf[r*132 + c*4] = gx[idx];
    }
  }
  __syncthreads();

  float acc[16];
  // ---- layer 1: D=128 -> 16 outputs of H
  #pragma unroll
  for (int i=0;i<16;i++) acc[i] = b1[k*H_ + h0 + i];
  #pragma unroll 2
  for (int d4=0; d4<D_/4; d4++) {
    float4 xv = *(const float4*)&xbuf[lane*132 + d4*4];
    const float* wd = w1 + d4*4*H_ + h0;
    #pragma unroll
    for (int i=0;i<16;i++) acc[i] = fmaf(xv.x, wd[i], acc[i]);
    #pragma unroll
    for (int i=0;i<16;i++) acc[i] = fmaf(xv.y, wd[H_+i], acc[i]);
    #pragma unroll
    for (int i=0;i<16;i++) acc[i] = fmaf(xv.z, wd[2*H_+i], acc[i]);
    #pragma unroll
    for (int i=0;i<16;i++) acc[i] = fmaf(xv.w, wd[3*H_+i], acc[i]);
  }
  #pragma unroll
  for (int i=0;i<16;i+=4) {
    float4 v;
    v.x = softplus_f(acc[i+0]); v.y = softplus_f(acc[i+1]);
    v.z = softplus_f(acc[i+2]); v.w = softplus_f(acc[i+3]);
    *(float4*)&hbuf[lane*68 + h0 + i] = v;
  }
  __syncthreads();
  // ---- layer 2
  #pragma unroll
  for (int i=0;i<16;i++) acc[i] = b2[k*H_ + h0 + i];
  #pragma unroll 2
  for (int h4=0; h4<H_/4; h4++) {
    float4 hv = *(const float4*)&hbuf[lane*68 + h4*4];
    const float* wd = w2 + h4*4*H_ + h0;
    #pragma unroll
    for (int i=0;i<16;i++) acc[i] = fmaf(hv.x, wd[i], acc[i]);
    #pragma unroll
    for (int i=0;i<16;i++) acc[i] = fmaf(hv.y, wd[H_+i], acc[i]);
    #pragma unroll
    for (int i=0;i<16;i++) acc[i] = fmaf(hv.z, wd[2*H_+i], acc[i]);
    #pragma unroll
    for (int i=0;i<16;i++) acc[i] = fmaf(hv.w, wd[3*H_+i], acc[i]);
  }
  __syncthreads();  // all reads of h1 done
  #pragma unroll
  for (int i=0;i<16;i+=4) {
    float4 v;
    v.x = softplus_f(acc[i+0]); v.y = softplus_f(acc[i+1]);
    v.z = softplus_f(acc[i+2]); v.w = softplus_f(acc[i+3]);
    *(float4*)&hbuf[lane*68 + h0 + i] = v;
  }
  __syncthreads();
  // ---- layer 3 (no activation)
  #pragma unroll
  for (int i=0;i<16;i++) acc[i] = b3[k*H_ + h0 + i];
  #pragma unroll 2
  for (int h4=0; h4<H_/4; h4++) {
    float4 hv = *(const float4*)&hbuf[lane*68 + h4*4];
    const float* wd = w3 + h4*4*H_ + h0;
    #pragma unroll
    for (int i=0;i<16;i++) acc[i] = fmaf(hv.x, wd[i], acc[i]);
    #pragma unroll
    for (int i=0;i<16;i++) acc[i] = fmaf(hv.y, wd[H_+i], acc[i]);
    #pragma unroll
    for (int i=0;i<16;i++) acc[i] = fmaf(hv.z, wd[2*H_+i], acc[i]);
    #pragma unroll
    for (int i=0;i<16;i++) acc[i] = fmaf(hv.w, wd[3*H_+i], acc[i]);
  }
  // ---- scale by sqrt(c2_k), round to fp16, norms from ROUNDED values
  float lsv = log_sigma[k];
  float inv2sig = 0.5f * exp2f(-lsv * 3.32192809489f);  // 1/(2*10^ls)
  float c2 = inv2sig * 1.44269504089f;                  // * log2(e)
  float s = sqrtf(c2);
  half8 u0, u1;
  float nsum = 0.f;
  #pragma unroll
  for (int i=0;i<8;i++) {
    _Float16 v = (_Float16)(s * acc[i]);
    u0[i] = v; float f = (float)v; nsum = fmaf(f, f, nsum);
  }
  #pragma unroll
  for (int i=0;i<8;i++) {
    _Float16 v = (_Float16)(s * acc[8+i]);
    u1[i] = v; float f = (float)v; nsum = fmaf(f, f, nsum);
  }
  // fragment-native store: chunk c = row/16, tile [ks][fq][fr][8].
  {
    const int c16 = row >> 4;
    const int frp = row & 15;
    const int ks0 = wv >> 1;
    const int fq0 = (wv & 1) * 2;
    _Float16* dp = dsth + ((size_t)(k*(nrows >> 4) + c16))*1024
                        + ks0*512 + fq0*128 + frp*8;
    *(half8*)dp = u0;
    *(half8*)(dp + 128) = u1;   // next fq
  }
  nred[lane*4 + wv] = nsum;
  __syncthreads();
  if (t < 64) {
    float v = nred[t*4+0] + nred[t*4+1] + nred[t*4+2] + nred[t*4+3];
    dstn[(size_t)k*nrows + row] = v;
  }
}

// ---------------- main: barrier-free MFMA dot + exp + weighted sum ----------------
// No __syncthreads. Fragments load straight from L2-resident fxh/fzh
// (fragment-native layout -> fully-coalesced dwordx4 loads). Epilogue stores
// staged through a PER-WAVE LDS tile (wave-synchronous) -> full-line dwordx4.
__global__ __launch_bounds__(256, 3) void dkef_main(
    const _Float16* __restrict__ fxh, const _Float16* __restrict__ fzh,
    const float* __restrict__ nxs, const float* __restrict__ nzs,
    const float* __restrict__ kw, float* __restrict__ out)
{
  // per-wave 16x64 staging tile, row stride 68 floats (272B, 16B-aligned)
  __shared__ __align__(16) float obuf[4][16*68 + 4];

  const int t = threadIdx.x;
  const int lane = t & 63;
  const int wv = t >> 6;           // 0..3

  // XCD-chunked swizzle (bijective: 4096 blocks = 8 * 512): per-XCD working
  // set = fzh (1.6MB) + fxh n-chunk (0.8MB) < 4MiB L2.
  const int NTM = M_/128;                         // 32
  const int orig = blockIdx.y * NTM + blockIdx.x; // flatten, x fastest
  const int swz = (orig & 7) * ((NTM*(N_/128)) >> 3) + (orig >> 3);
  const int m0 = (swz % NTM) * 128;
  const int n0 = (swz / NTM) * 128;

  // softmax over kernel_weights (3 values), computed redundantly per thread
  float k0 = kw[0], k1 = kw[1], k2 = kw[2];
  float mx = fmaxf(k0, fmaxf(k1, k2));
  float e0 = exp2f((k0 - mx) * 1.44269504089f);
  float e1 = exp2f((k1 - mx) * 1.44269504089f);
  float e2 = exp2f((k2 - mx) * 1.44269504089f);
  float winv = 1.0f / (e0 + e1 + e2);
  float wk3[3] = {e0 * winv, e1 * winv, e2 * winv};

  const int wa = (wv >> 1) * 64;   // n-half within block tile
  const int wb = (wv & 1) * 64;    // m-half
  const int fr = lane & 15;        // frag row/col
  const int fq = lane >> 4;        // quad

  floatx4 oacc[4][4] = {};

  const int cn = (n0 + wa) >> 4;   // 16-row chunk indices
  const int cm = (m0 + wb) >> 4;

  for (int k = 0; k < K_; k++) {
    // fragment loads: 1024 B contiguous per instr (8 full lines), L2-hot
    const _Float16* pa = fxh + ((size_t)(k*(N_/16) + cn))*1024 + fq*128 + fr*8;
    const _Float16* pb = fzh + ((size_t)(k*(M_/16) + cm))*1024 + fq*128 + fr*8;
    half8 bf[4][2];
    #pragma unroll
    for (int j = 0; j < 4; j++) {
      bf[j][0] = *(const half8*)(pb + j*1024);
      bf[j][1] = *(const half8*)(pb + j*1024 + 512);
    }
    floatx4 nx4[4];
    float nzv[4];
    #pragma unroll
    for (int i = 0; i < 4; i++)
      nx4[i] = *(const floatx4*)&nxs[(size_t)k*N_ + n0 + wa + i*16 + fq*4];
    #pragma unroll
    for (int j = 0; j < 4; j++)
      nzv[j] = nzs[(size_t)k*M_ + m0 + wb + j*16 + fr];

    float wkv = wk3[k];
    #pragma unroll
    for (int i = 0; i < 4; i++) {
      half8 a0 = *(const half8*)(pa + i*1024);
      half8 a1 = *(const half8*)(pa + i*1024 + 512);
      #pragma unroll
      for (int j = 0; j < 4; j++) {
        floatx4 d = {};
        d = __builtin_amdgcn_mfma_f32_16x16x32_f16(a0, bf[j][0], d, 0, 0, 0);
        d = __builtin_amdgcn_mfma_f32_16x16x32_f16(a1, bf[j][1], d, 0, 0, 0);
        // epilogue fused per tile: out += w_k * 2^min(2*dot - (nx+nz), 0)
        #pragma unroll
        for (int r = 0; r < 4; r++) {
          float sm = nx4[i][r] + nzv[j];
          float e = fmaf(2.0f, d[r], -sm);
          e = fminf(e, 0.0f);
          oacc[i][j][r] = fmaf(wkv, exp2f(e), oacc[i][j][r]);
        }
      }
    }
  }

  // store 128x128 tile via wave-private LDS -> full-line dwordx4 stores.
  float* ob = &obuf[wv][0];
  #pragma unroll
  for (int i = 0; i < 4; i++) {
    #pragma unroll
    for (int j = 0; j < 4; j++)
      #pragma unroll
      for (int r = 0; r < 4; r++)
        ob[(fq*4 + r)*68 + j*16 + fr] = oacc[i][j][r];
    #pragma unroll
    for (int s = 0; s < 4; s++) {
      floatx4 v = *(const floatx4*)&ob[(s*4 + fq)*68 + fr*4];
      size_t rowg = (size_t)(n0 + wa + i*16 + s*4 + fq);
      float* orow = out + rowg * M_ + m0 + wb + fr*4;
      __builtin_nontemporal_store(v, (floatx4*)orow);
    }
  }
}

extern "C" void kernel_launch(void* const* d_in, const int* in_sizes, int n_in,
                              void* d_out, int out_size, void* d_ws, size_t ws_size,
                              hipStream_t stream) {
  const float* x  = (const float*)d_in[0];
  const float* z  = (const float*)d_in[1];
  const float* W1 = (const float*)d_in[2];
  const float* b1 = (const float*)d_in[3];
  const float* W2 = (const float*)d_in[4];
  const float* b2 = (const float*)d_in[5];
  const float* W3 = (const float*)d_in[6];
  const float* b3 = (const float*)d_in[7];
  const float* ls = (const float*)d_in[8];
  const float* kw = (const float*)d_in[9];
  float* out = (float*)d_out;

  char* ws = (char*)d_ws;
  _Float16* fxh = (_Float16*)(ws + OFF_FXH);
  _Float16* fzh = (_Float16*)(ws + OFF_FZH);
  float* nxs = (float*)(ws + OFF_NXS);
  float* nzs = (float*)(ws + OFF_NZS);
  float* W1t = (float*)(ws + OFF_W1T);
  float* W2t = (float*)(ws + OFF_W2T);
  float* W3t = (float*)(ws + OFF_W3T);

  hipLaunchKernelGGL(transpose_w, dim3((K_*H_*D_ + 255)/256), dim3(256), 0, stream,
                     W1, W2, W3, W1t, W2t, W3t);
  hipLaunchKernelGGL(phi_kernel, dim3(N_/64, K_, 2), dim3(256), 0, stream,
                     x, z, W1t, b1, W2t, b2, W3t, b3, ls, fxh, nxs, fzh, nzs);
  // ATTRIBUTION: dkef_main is idempotent -> 4x launch; dkef = (dur-356.3)/3
  hipLaunchKernelGGL(dkef_main, dim3(M_/128, N_/128), dim3(256), 0, stream,
                     fxh, fzh, nxs, nzs, kw, out);
  hipLaunchKernelGGL(dkef_main, dim3(M_/128, N_/128), dim3(256), 0, stream,
                     fxh, fzh, nxs, nzs, kw, out);
  hipLaunchKernelGGL(dkef_main, dim3(M_/128, N_/128), dim3(256), 0, stream,
                     fxh, fzh, nxs, nzs, kw, out);
  hipLaunchKernelGGL(dkef_main, dim3(M_/128, N_/128), dim3(256), 0, stream,
                     fxh, fzh, nxs, nzs, kw, out);
}

// Round 6
// 431.196 us; speedup vs baseline: 1.2906x; 1.2906x over previous
//
#include <hip/hip_runtime.h>

typedef _Float16 half8 __attribute__((ext_vector_type(8)));
typedef float floatx4 __attribute__((ext_vector_type(4)));

#define K_ 3
#define N_ 16384
#define M_ 4096
#define D_ 128
#define H_ 64

// workspace layout (bytes)
#define OFF_FXH 0
#define SZ_FXH (K_*N_*H_*2)
#define OFF_FZH (OFF_FXH + SZ_FXH)
#define SZ_FZH (K_*M_*H_*2)
#define OFF_NXS (OFF_FZH + SZ_FZH)
#define SZ_NXS (K_*N_*4)
#define OFF_NZS (OFF_NXS + SZ_NXS)
#define SZ_NZS (K_*M_*4)
#define OFF_W1T (OFF_NZS + SZ_NZS)
#define SZ_W1T (K_*D_*H_*4)
#define OFF_W2T (OFF_W1T + SZ_W1T)
#define SZ_W2T (K_*H_*H_*4)
#define OFF_W3T (OFF_W2T + SZ_W2T)

// PROBE ROUND (attribution established: fill~168, phi~119 (9x over floor),
// dkef~67, transpose~3).
//  - phi_kernel runs rep=2 internally -> ~237us dispatch -> enters rocprof
//    top-5 -> first-ever counter row for phi (VGPR/SGPR/VALUBusy/Occ).
//  - phi_probe_ldsw = LDS-broadcast-weight variant, launched BEFORE the real
//    phi (outputs overwritten -> zero correctness risk); its dur falls out of
//    the subtraction. Tests H1: uniform weight loads are hitting a slow
//    VMEM-broadcast path instead of s_load/SGPR.

// fxh/fzh are stored FRAGMENT-NATIVE: for each k and 16-row chunk c,
// a 1024-half (2 KB) tile laid out [ks(2)][fq(4)][fr(16)][e(8)].
// A dkef MFMA fragment load (lane&15=fr, lane>>4=fq) is then
// 64 lanes x 16 B = 1024 B CONTIGUOUS -> 8 full cache lines.

// ---------------- weight transpose (tiny) ----------------
__global__ void transpose_w(const float* __restrict__ W1,
                            const float* __restrict__ W2,
                            const float* __restrict__ W3,
                            float* __restrict__ W1t,
                            float* __restrict__ W2t,
                            float* __restrict__ W3t) {
  int idx = blockIdx.x * 256 + threadIdx.x;
  if (idx < K_*H_*D_) {   // W1[k][h][d] -> W1t[k][d][h]
    int k = idx / (H_*D_); int r = idx % (H_*D_);
    int h = r / D_; int d = r % D_;
    W1t[k*(D_*H_) + d*H_ + h] = W1[idx];
  }
  if (idx < K_*H_*H_) {   // W2[k][g][h] -> W2t[k][h][g]; same for W3
    int k = idx / (H_*H_); int r = idx % (H_*H_);
    int g = r / H_; int h = r % H_;
    W2t[k*(H_*H_) + h*H_ + g] = W2[idx];
    W3t[k*(H_*H_) + h*H_ + g] = W3[idx];
  }
}

__device__ __forceinline__ float softplus_f(float x) {
  float p = exp2f(x * 1.44269504089f);
  float r = 0.693147180560f * log2f(1.0f + p);
  return (x > 20.0f) ? x : r;
}

// ---------------- phi PROBE: weights via LDS broadcast ----------------
// Same math/grid as phi_kernel; weights staged in 8KB chunks into LDS and
// read as wave-uniform ds_read_b128 broadcasts (conflict-free). x read as
// per-lane row gather (round-0/1 behavior). 26.4KB LDS -> 4 blocks/CU.
__global__ __launch_bounds__(256) void phi_probe_ldsw(
    const float* __restrict__ x, const float* __restrict__ z,
    const float* __restrict__ W1t, const float* __restrict__ b1,
    const float* __restrict__ W2t, const float* __restrict__ b2,
    const float* __restrict__ W3t, const float* __restrict__ b3,
    const float* __restrict__ log_sigma,
    _Float16* __restrict__ fxh, float* __restrict__ nxs,
    _Float16* __restrict__ fzh, float* __restrict__ nzs)
{
  __shared__ __align__(16) float wlds[2048];   // 32 in-dims x 64 out-h chunk
  __shared__ float hbuf[64*68];
  __shared__ float nred[64*4];

  const int which = blockIdx.z;
  const int nrows = which ? M_ : N_;
  if (blockIdx.x * 64 >= nrows) return;
  const float* __restrict__ src = which ? z : x;
  _Float16* __restrict__ dsth = which ? fzh : fxh;
  float* __restrict__ dstn = which ? nzs : nxs;

  const int t = threadIdx.x;
  const int lane = t & 63;
  const int wv = __builtin_amdgcn_readfirstlane(t >> 6);
  const int k = blockIdx.y;
  const int row = blockIdx.x * 64 + lane;
  const int h0 = wv * 16;

  const float* __restrict__ w1 = W1t + k*(D_*H_);
  const float* __restrict__ w2 = W2t + k*(H_*H_);
  const float* __restrict__ w3 = W3t + k*(H_*H_);
  const float* __restrict__ srcrow = src + (size_t)row * D_;

  float acc[16];
  // ---- layer 1: 4 chunks of 32 d
  #pragma unroll
  for (int i=0;i<16;i++) acc[i] = b1[k*H_ + h0 + i];
  for (int c = 0; c < 4; c++) {
    __syncthreads();   // prev chunk FMAs done / hbuf ready next layers
    #pragma unroll
    for (int it = 0; it < 2; it++) {
      int idx = t + it*256;
      *(float4*)&wlds[idx*4] = *(const float4*)&w1[c*2048 + idx*4];
    }
    __syncthreads();
    #pragma unroll
    for (int d4 = 0; d4 < 8; d4++) {
      float4 xv = *(const float4*)(srcrow + c*32 + d4*4);
      float xs4[4] = {xv.x, xv.y, xv.z, xv.w};
      #pragma unroll
      for (int dd = 0; dd < 4; dd++) {
        const float* wr = &wlds[(d4*4+dd)*H_ + h0];
        float4 w0 = *(const float4*)&wr[0];
        float4 w1v = *(const float4*)&wr[4];
        float4 w2v = *(const float4*)&wr[8];
        float4 w3v = *(const float4*)&wr[12];
        float xs = xs4[dd];
        acc[0]=fmaf(xs,w0.x,acc[0]);  acc[1]=fmaf(xs,w0.y,acc[1]);
        acc[2]=fmaf(xs,w0.z,acc[2]);  acc[3]=fmaf(xs,w0.w,acc[3]);
        acc[4]=fmaf(xs,w1v.x,acc[4]); acc[5]=fmaf(xs,w1v.y,acc[5]);
        acc[6]=fmaf(xs,w1v.z,acc[6]); acc[7]=fmaf(xs,w1v.w,acc[7]);
        acc[8]=fmaf(xs,w2v.x,acc[8]); acc[9]=fmaf(xs,w2v.y,acc[9]);
        acc[10]=fmaf(xs,w2v.z,acc[10]); acc[11]=fmaf(xs,w2v.w,acc[11]);
        acc[12]=fmaf(xs,w3v.x,acc[12]); acc[13]=fmaf(xs,w3v.y,acc[13]);
        acc[14]=fmaf(xs,w3v.z,acc[14]); acc[15]=fmaf(xs,w3v.w,acc[15]);
      }
    }
  }
  __syncthreads();  // last chunk FMAs done everywhere before hbuf write
  #pragma unroll
  for (int i=0;i<16;i+=4) {
    float4 v;
    v.x = softplus_f(acc[i+0]); v.y = softplus_f(acc[i+1]);
    v.z = softplus_f(acc[i+2]); v.w = softplus_f(acc[i+3]);
    *(float4*)&hbuf[lane*68 + h0 + i] = v;
  }
  // ---- layer 2: 2 chunks of 32 h-in
  #pragma unroll
  for (int i=0;i<16;i++) acc[i] = b2[k*H_ + h0 + i];
  for (int c = 0; c < 2; c++) {
    __syncthreads();
    #pragma unroll
    for (int it = 0; it < 2; it++) {
      int idx = t + it*256;
      *(float4*)&wlds[idx*4] = *(const float4*)&w2[c*2048 + idx*4];
    }
    __syncthreads();
    #pragma unroll
    for (int h4 = 0; h4 < 8; h4++) {
      float4 hv = *(const float4*)&hbuf[lane*68 + c*32 + h4*4];
      float hs4[4] = {hv.x, hv.y, hv.z, hv.w};
      #pragma unroll
      for (int dd = 0; dd < 4; dd++) {
        const float* wr = &wlds[(h4*4+dd)*H_ + h0];
        float4 w0 = *(const float4*)&wr[0];
        float4 w1v = *(const float4*)&wr[4];
        float4 w2v = *(const float4*)&wr[8];
        float4 w3v = *(const float4*)&wr[12];
        float xs = hs4[dd];
        acc[0]=fmaf(xs,w0.x,acc[0]);  acc[1]=fmaf(xs,w0.y,acc[1]);
        acc[2]=fmaf(xs,w0.z,acc[2]);  acc[3]=fmaf(xs,w0.w,acc[3]);
        acc[4]=fmaf(xs,w1v.x,acc[4]); acc[5]=fmaf(xs,w1v.y,acc[5]);
        acc[6]=fmaf(xs,w1v.z,acc[6]); acc[7]=fmaf(xs,w1v.w,acc[7]);
        acc[8]=fmaf(xs,w2v.x,acc[8]); acc[9]=fmaf(xs,w2v.y,acc[9]);
        acc[10]=fmaf(xs,w2v.z,acc[10]); acc[11]=fmaf(xs,w2v.w,acc[11]);
        acc[12]=fmaf(xs,w3v.x,acc[12]); acc[13]=fmaf(xs,w3v.y,acc[13]);
        acc[14]=fmaf(xs,w3v.z,acc[14]); acc[15]=fmaf(xs,w3v.w,acc[15]);
      }
    }
  }
  __syncthreads();
  float h2v[16];
  #pragma unroll
  for (int i=0;i<16;i++) h2v[i] = softplus_f(acc[i]);
  #pragma unroll
  for (int i=0;i<16;i+=4)
    *(float4*)&hbuf[lane*68 + h0 + i] = *(float4*)&h2v[i];
  // ---- layer 3
  #pragma unroll
  for (int i=0;i<16;i++) acc[i] = b3[k*H_ + h0 + i];
  for (int c = 0; c < 2; c++) {
    __syncthreads();
    #pragma unroll
    for (int it = 0; it < 2; it++) {
      int idx = t + it*256;
      *(float4*)&wlds[idx*4] = *(const float4*)&w3[c*2048 + idx*4];
    }
    __syncthreads();
    #pragma unroll
    for (int h4 = 0; h4 < 8; h4++) {
      float4 hv = *(const float4*)&hbuf[lane*68 + c*32 + h4*4];
      float hs4[4] = {hv.x, hv.y, hv.z, hv.w};
      #pragma unroll
      for (int dd = 0; dd < 4; dd++) {
        const float* wr = &wlds[(h4*4+dd)*H_ + h0];
        float4 w0 = *(const float4*)&wr[0];
        float4 w1v = *(const float4*)&wr[4];
        float4 w2v = *(const float4*)&wr[8];
        float4 w3v = *(const float4*)&wr[12];
        float xs = hs4[dd];
        acc[0]=fmaf(xs,w0.x,acc[0]);  acc[1]=fmaf(xs,w0.y,acc[1]);
        acc[2]=fmaf(xs,w0.z,acc[2]);  acc[3]=fmaf(xs,w0.w,acc[3]);
        acc[4]=fmaf(xs,w1v.x,acc[4]); acc[5]=fmaf(xs,w1v.y,acc[5]);
        acc[6]=fmaf(xs,w1v.z,acc[6]); acc[7]=fmaf(xs,w1v.w,acc[7]);
        acc[8]=fmaf(xs,w2v.x,acc[8]); acc[9]=fmaf(xs,w2v.y,acc[9]);
        acc[10]=fmaf(xs,w2v.z,acc[10]); acc[11]=fmaf(xs,w2v.w,acc[11]);
        acc[12]=fmaf(xs,w3v.x,acc[12]); acc[13]=fmaf(xs,w3v.y,acc[13]);
        acc[14]=fmaf(xs,w3v.z,acc[14]); acc[15]=fmaf(xs,w3v.w,acc[15]);
      }
    }
  }
  // ---- scale, fp16 round, norms, fragment-native store
  float lsv = log_sigma[k];
  float inv2sig = 0.5f * exp2f(-lsv * 3.32192809489f);
  float c2 = inv2sig * 1.44269504089f;
  float s = sqrtf(c2);
  half8 u0, u1;
  float nsum = 0.f;
  #pragma unroll
  for (int i=0;i<8;i++) {
    _Float16 v = (_Float16)(s * acc[i]);
    u0[i] = v; float f = (float)v; nsum = fmaf(f, f, nsum);
  }
  #pragma unroll
  for (int i=0;i<8;i++) {
    _Float16 v = (_Float16)(s * acc[8+i]);
    u1[i] = v; float f = (float)v; nsum = fmaf(f, f, nsum);
  }
  {
    const int c16 = row >> 4;
    const int frp = row & 15;
    const int ks0 = wv >> 1;
    const int fq0 = (wv & 1) * 2;
    _Float16* dp = dsth + ((size_t)(k*(nrows >> 4) + c16))*1024
                        + ks0*512 + fq0*128 + frp*8;
    *(half8*)dp = u0;
    *(half8*)(dp + 128) = u1;
  }
  nred[lane*4 + wv] = nsum;
  __syncthreads();
  if (t < 64) {
    float v = nred[t*4+0] + nred[t*4+1] + nred[t*4+2] + nred[t*4+3];
    dstn[(size_t)k*nrows + row] = v;
  }
}

// ---------------- phi (real): current structure, rep=2 for counter visibility
__global__ __launch_bounds__(256) void phi_kernel(
    const float* __restrict__ x, const float* __restrict__ z,
    const float* __restrict__ W1t, const float* __restrict__ b1,
    const float* __restrict__ W2t, const float* __restrict__ b2,
    const float* __restrict__ W3t, const float* __restrict__ b3,
    const float* __restrict__ log_sigma,
    _Float16* __restrict__ fxh, float* __restrict__ nxs,
    _Float16* __restrict__ fzh, float* __restrict__ nzs)
{
  __shared__ float xbuf[64*132];
  __shared__ float hbuf[64*68];
  __shared__ float nred[64*4];

  const int which = blockIdx.z;
  const int nrows = which ? M_ : N_;
  if (blockIdx.x * 64 >= nrows) return;
  const float* __restrict__ src = which ? z : x;
  _Float16* __restrict__ dsth = which ? fzh : fxh;
  float* __restrict__ dstn = which ? nzs : nxs;

  const int t = threadIdx.x;
  const int lane = t & 63;
  const int wv = __builtin_amdgcn_readfirstlane(t >> 6);
  const int k = blockIdx.y;
  const int row0 = blockIdx.x * 64;
  const int row = row0 + lane;
  const int h0 = wv * 16;

  const float* __restrict__ w1 = W1t + k*(D_*H_);
  const float* __restrict__ w2 = W2t + k*(H_*H_);
  const float* __restrict__ w3 = W3t + k*(H_*H_);

  {
    const float4* __restrict__ gx = (const float4*)(src + (size_t)row0 * D_);
    #pragma unroll
    for (int it = 0; it < 8; it++) {
      int idx = t + it*256;
      int r = idx >> 5, c = idx & 31;
      *(float4*)&xbuf[r*132 + c*4] = gx[idx];
    }
  }
  __syncthreads();

  // REP=2 probe: second pass recomputes + re-stores identical values.
  // memory clobber prevents CSE/hoisting of the whole pass.
  for (int rep = 0; rep < 2; ++rep) {
  asm volatile("" ::: "memory");
  float acc[16];
  #pragma unroll
  for (int i=0;i<16;i++) acc[i] = b1[k*H_ + h0 + i];
  #pragma unroll 2
  for (int d4=0; d4<D_/4; d4++) {
    float4 xv = *(const float4*)&xbuf[lane*132 + d4*4];
    const float* wd = w1 + d4*4*H_ + h0;
    #pragma unroll
    for (int i=0;i<16;i++) acc[i] = fmaf(xv.x, wd[i], acc[i]);
    #pragma unroll
    for (int i=0;i<16;i++) acc[i] = fmaf(xv.y, wd[H_+i], acc[i]);
    #pragma unroll
    for (int i=0;i<16;i++) acc[i] = fmaf(xv.z, wd[2*H_+i], acc[i]);
    #pragma unroll
    for (int i=0;i<16;i++) acc[i] = fmaf(xv.w, wd[3*H_+i], acc[i]);
  }
  #pragma unroll
  for (int i=0;i<16;i+=4) {
    float4 v;
    v.x = softplus_f(acc[i+0]); v.y = softplus_f(acc[i+1]);
    v.z = softplus_f(acc[i+2]); v.w = softplus_f(acc[i+3]);
    *(float4*)&hbuf[lane*68 + h0 + i] = v;
  }
  __syncthreads();
  #pragma unroll
  for (int i=0;i<16;i++) acc[i] = b2[k*H_ + h0 + i];
  #pragma unroll 2
  for (int h4=0; h4<H_/4; h4++) {
    float4 hv = *(const float4*)&hbuf[lane*68 + h4*4];
    const float* wd = w2 + h4*4*H_ + h0;
    #pragma unroll
    for (int i=0;i<16;i++) acc[i] = fmaf(hv.x, wd[i], acc[i]);
    #pragma unroll
    for (int i=0;i<16;i++) acc[i] = fmaf(hv.y, wd[H_+i], acc[i]);
    #pragma unroll
    for (int i=0;i<16;i++) acc[i] = fmaf(hv.z, wd[2*H_+i], acc[i]);
    #pragma unroll
    for (int i=0;i<16;i++) acc[i] = fmaf(hv.w, wd[3*H_+i], acc[i]);
  }
  __syncthreads();
  #pragma unroll
  for (int i=0;i<16;i+=4) {
    float4 v;
    v.x = softplus_f(acc[i+0]); v.y = softplus_f(acc[i+1]);
    v.z = softplus_f(acc[i+2]); v.w = softplus_f(acc[i+3]);
    *(float4*)&hbuf[lane*68 + h0 + i] = v;
  }
  __syncthreads();
  #pragma unroll
  for (int i=0;i<16;i++) acc[i] = b3[k*H_ + h0 + i];
  #pragma unroll 2
  for (int h4=0; h4<H_/4; h4++) {
    float4 hv = *(const float4*)&hbuf[lane*68 + h4*4];
    const float* wd = w3 + h4*4*H_ + h0;
    #pragma unroll
    for (int i=0;i<16;i++) acc[i] = fmaf(hv.x, wd[i], acc[i]);
    #pragma unroll
    for (int i=0;i<16;i++) acc[i] = fmaf(hv.y, wd[H_+i], acc[i]);
    #pragma unroll
    for (int i=0;i<16;i++) acc[i] = fmaf(hv.z, wd[2*H_+i], acc[i]);
    #pragma unroll
    for (int i=0;i<16;i++) acc[i] = fmaf(hv.w, wd[3*H_+i], acc[i]);
  }
  float lsv = log_sigma[k];
  float inv2sig = 0.5f * exp2f(-lsv * 3.32192809489f);
  float c2 = inv2sig * 1.44269504089f;
  float s = sqrtf(c2);
  half8 u0, u1;
  float nsum = 0.f;
  #pragma unroll
  for (int i=0;i<8;i++) {
    _Float16 v = (_Float16)(s * acc[i]);
    u0[i] = v; float f = (float)v; nsum = fmaf(f, f, nsum);
  }
  #pragma unroll
  for (int i=0;i<8;i++) {
    _Float16 v = (_Float16)(s * acc[8+i]);
    u1[i] = v; float f = (float)v; nsum = fmaf(f, f, nsum);
  }
  {
    const int c16 = row >> 4;
    const int frp = row & 15;
    const int ks0 = wv >> 1;
    const int fq0 = (wv & 1) * 2;
    _Float16* dp = dsth + ((size_t)(k*(nrows >> 4) + c16))*1024
                        + ks0*512 + fq0*128 + frp*8;
    *(half8*)dp = u0;
    *(half8*)(dp + 128) = u1;
  }
  nred[lane*4 + wv] = nsum;
  __syncthreads();
  if (t < 64) {
    float v = nred[t*4+0] + nred[t*4+1] + nred[t*4+2] + nred[t*4+3];
    dstn[(size_t)k*nrows + row] = v;
  }
  __syncthreads();   // make rep-1 writes safe against rep-0 nred reads
  }
}

// ---------------- main: barrier-free MFMA dot + exp + weighted sum ----------------
// (byte-identical to round 4)
__global__ __launch_bounds__(256, 3) void dkef_main(
    const _Float16* __restrict__ fxh, const _Float16* __restrict__ fzh,
    const float* __restrict__ nxs, const float* __restrict__ nzs,
    const float* __restrict__ kw, float* __restrict__ out)
{
  __shared__ __align__(16) float obuf[4][16*68 + 4];

  const int t = threadIdx.x;
  const int lane = t & 63;
  const int wv = t >> 6;

  const int NTM = M_/128;
  const int orig = blockIdx.y * NTM + blockIdx.x;
  const int swz = (orig & 7) * ((NTM*(N_/128)) >> 3) + (orig >> 3);
  const int m0 = (swz % NTM) * 128;
  const int n0 = (swz / NTM) * 128;

  float k0 = kw[0], k1 = kw[1], k2 = kw[2];
  float mx = fmaxf(k0, fmaxf(k1, k2));
  float e0 = exp2f((k0 - mx) * 1.44269504089f);
  float e1 = exp2f((k1 - mx) * 1.44269504089f);
  float e2 = exp2f((k2 - mx) * 1.44269504089f);
  float winv = 1.0f / (e0 + e1 + e2);
  float wk3[3] = {e0 * winv, e1 * winv, e2 * winv};

  const int wa = (wv >> 1) * 64;
  const int wb = (wv & 1) * 64;
  const int fr = lane & 15;
  const int fq = lane >> 4;

  floatx4 oacc[4][4] = {};

  const int cn = (n0 + wa) >> 4;
  const int cm = (m0 + wb) >> 4;

  for (int k = 0; k < K_; k++) {
    const _Float16* pa = fxh + ((size_t)(k*(N_/16) + cn))*1024 + fq*128 + fr*8;
    const _Float16* pb = fzh + ((size_t)(k*(M_/16) + cm))*1024 + fq*128 + fr*8;
    half8 bf[4][2];
    #pragma unroll
    for (int j = 0; j < 4; j++) {
      bf[j][0] = *(const half8*)(pb + j*1024);
      bf[j][1] = *(const half8*)(pb + j*1024 + 512);
    }
    floatx4 nx4[4];
    float nzv[4];
    #pragma unroll
    for (int i = 0; i < 4; i++)
      nx4[i] = *(const floatx4*)&nxs[(size_t)k*N_ + n0 + wa + i*16 + fq*4];
    #pragma unroll
    for (int j = 0; j < 4; j++)
      nzv[j] = nzs[(size_t)k*M_ + m0 + wb + j*16 + fr];

    float wkv = wk3[k];
    #pragma unroll
    for (int i = 0; i < 4; i++) {
      half8 a0 = *(const half8*)(pa + i*1024);
      half8 a1 = *(const half8*)(pa + i*1024 + 512);
      #pragma unroll
      for (int j = 0; j < 4; j++) {
        floatx4 d = {};
        d = __builtin_amdgcn_mfma_f32_16x16x32_f16(a0, bf[j][0], d, 0, 0, 0);
        d = __builtin_amdgcn_mfma_f32_16x16x32_f16(a1, bf[j][1], d, 0, 0, 0);
        #pragma unroll
        for (int r = 0; r < 4; r++) {
          float sm = nx4[i][r] + nzv[j];
          float e = fmaf(2.0f, d[r], -sm);
          e = fminf(e, 0.0f);
          oacc[i][j][r] = fmaf(wkv, exp2f(e), oacc[i][j][r]);
        }
      }
    }
  }

  float* ob = &obuf[wv][0];
  #pragma unroll
  for (int i = 0; i < 4; i++) {
    #pragma unroll
    for (int j = 0; j < 4; j++)
      #pragma unroll
      for (int r = 0; r < 4; r++)
        ob[(fq*4 + r)*68 + j*16 + fr] = oacc[i][j][r];
    #pragma unroll
    for (int s = 0; s < 4; s++) {
      floatx4 v = *(const floatx4*)&ob[(s*4 + fq)*68 + fr*4];
      size_t rowg = (size_t)(n0 + wa + i*16 + s*4 + fq);
      float* orow = out + rowg * M_ + m0 + wb + fr*4;
      __builtin_nontemporal_store(v, (floatx4*)orow);
    }
  }
}

extern "C" void kernel_launch(void* const* d_in, const int* in_sizes, int n_in,
                              void* d_out, int out_size, void* d_ws, size_t ws_size,
                              hipStream_t stream) {
  const float* x  = (const float*)d_in[0];
  const float* z  = (const float*)d_in[1];
  const float* W1 = (const float*)d_in[2];
  const float* b1 = (const float*)d_in[3];
  const float* W2 = (const float*)d_in[4];
  const float* b2 = (const float*)d_in[5];
  const float* W3 = (const float*)d_in[6];
  const float* b3 = (const float*)d_in[7];
  const float* ls = (const float*)d_in[8];
  const float* kw = (const float*)d_in[9];
  float* out = (float*)d_out;

  char* ws = (char*)d_ws;
  _Float16* fxh = (_Float16*)(ws + OFF_FXH);
  _Float16* fzh = (_Float16*)(ws + OFF_FZH);
  float* nxs = (float*)(ws + OFF_NXS);
  float* nzs = (float*)(ws + OFF_NZS);
  float* W1t = (float*)(ws + OFF_W1T);
  float* W2t = (float*)(ws + OFF_W2T);
  float* W3t = (float*)(ws + OFF_W3T);

  hipLaunchKernelGGL(transpose_w, dim3((K_*H_*D_ + 255)/256), dim3(256), 0, stream,
                     W1, W2, W3, W1t, W2t, W3t);
  // probe first: its outputs are fully overwritten by the real phi below
  hipLaunchKernelGGL(phi_probe_ldsw, dim3(N_/64, K_, 2), dim3(256), 0, stream,
                     x, z, W1t, b1, W2t, b2, W3t, b3, ls, fxh, nxs, fzh, nzs);
  hipLaunchKernelGGL(phi_kernel, dim3(N_/64, K_, 2), dim3(256), 0, stream,
                     x, z, W1t, b1, W2t, b2, W3t, b3, ls, fxh, nxs, fzh, nzs);
  hipLaunchKernelGGL(dkef_main, dim3(M_/128, N_/128), dim3(256), 0, stream,
                     fxh, fzh, nxs, nzs, kw, out);
}